// Round 1
// 3561.081 us; speedup vs baseline: 1.1662x; 1.1662x over previous
//
#include <hip/hip_runtime.h>
#include <math.h>

typedef unsigned short u16;
typedef __bf16 bf16x8 __attribute__((ext_vector_type(8)));
typedef float f32x4 __attribute__((ext_vector_type(4)));
typedef unsigned long long u64;

__device__ __forceinline__ float bf2f(u16 u) {
    union { unsigned u32; float f; } c; c.u32 = ((unsigned)u) << 16; return c.f;
}
__device__ __forceinline__ u16 f2bf(float f) {
    unsigned u = __float_as_uint(f);
    unsigned r = u + 0x7fff + ((u >> 16) & 1);
    return (u16)(r >> 16);
}
// element i of a float tensor whose dtype (bf16 vs fp32) is runtime-detected
__device__ __forceinline__ float ldmix(const void* p, u64 i, int isbf) {
    return isbf ? bf2f(((const u16*)p)[i]) : ((const float*)p)[i];
}
// async global->LDS, 16B per lane. LDS dest is wave-uniform base + lane*16.
__device__ __forceinline__ void gll16(const u16* g, u16* l) {
    __builtin_amdgcn_global_load_lds(
        (const __attribute__((address_space(1))) void*)g,
        (__attribute__((address_space(3))) void*)l, 16, 0, 0);
}

// ---------------------------------------------------------------------------
// Dtype probe: sample 64 words of tok_emb (nonzero rows). If low-16 bits look
// like bf16 N(0,0.02) values (exp field in [100,126]) for >=40/64 lanes,
// inputs are bf16. fp32 mantissa bits hit that window only ~10% of the time.
// ---------------------------------------------------------------------------
__global__ void detect_kernel(const unsigned* __restrict__ tokw, int* __restrict__ flag)
{
    int i = threadIdx.x;  // 0..63
    unsigned w = tokw[768 + i];
    unsigned e = (w >> 7) & 0xFF;
    bool hit = (e >= 100) && (e <= 126) && ((w & 0x7FFFu) != 0);
    unsigned long long m = __ballot(hit);
    if (i == 0) flag[0] = (__popcll(m) >= 40) ? 1 : 0;
}

// ---------------------------------------------------------------------------
// Embedding: h = tok_emb[x] + seg_emb[segment] + PE (computed on device)
// Writes fp32 (residual path) AND bf16 (GEMM-A path).
// ---------------------------------------------------------------------------
__global__ __launch_bounds__(256) void embed_kernel(
    const int* __restrict__ x, const int* __restrict__ seg,
    const void* __restrict__ tok, const void* __restrict__ se,
    const int* __restrict__ flagp, float* __restrict__ hF, u16* __restrict__ hB)
{
    int isbf = *flagp;
    int t = blockIdx.x;
    int pos = t & 63;
    int tokid = x[t], sgid = seg[t];
    int tid = threadIdx.x;
#pragma unroll
    for (int i = 0; i < 3; i++) {
        int d = tid + i * 256;
        int p = d >> 1;
        float freq = powf(10000.0f, (float)p * (1.0f / 192.0f));
        float arg = (float)pos / freq;
        float pe = (d & 1) ? cosf(arg) : sinf(arg);
        float v = ldmix(tok, (u64)tokid * 768 + d, isbf)
                + ldmix(se, (u64)sgid * 768 + d, isbf) + pe;
        hF[(u64)t * 768 + d] = v;
        hB[(u64)t * 768 + d] = f2bf(v);
    }
}

// ---------------------------------------------------------------------------
// Transpose+stage layer l's 6 weight matrices to bf16 [N][K] layout.
// oS/oF are ELEMENT offsets of the layer within the square / FF weights.
// ---------------------------------------------------------------------------
__global__ __launch_bounds__(256) void transpose6(
    const void* __restrict__ wq, const void* __restrict__ wk,
    const void* __restrict__ wv, const void* __restrict__ wo,
    const void* __restrict__ w1, const void* __restrict__ w2,
    u16* __restrict__ out, const int* __restrict__ flagp, u64 oS, u64 oF)
{
    int isbf = *flagp;
    int id = blockIdx.x;
    const void* src; u16* dst; int R, C; u64 off;
    if (id < 2304) {
        int m = id / 576; id -= m * 576; R = 768; C = 768; off = oS;
        src = (m == 0) ? wq : (m == 1) ? wk : (m == 2) ? wv : wo;
        dst = out + (u64)m * 589824;
    } else if (id < 4608) {
        id -= 2304; R = 768; C = 3072; off = oF; src = w1; dst = out + 2359296;
    } else {
        id -= 4608; R = 3072; C = 768; off = oF; src = w2; dst = out + 4718592;
    }
    int tilesC = C >> 5;
    int tr = id / tilesC, tc = id % tilesC;
    __shared__ float tile[32][33];
    int rl = threadIdx.x >> 5, cl = threadIdx.x & 31;
#pragma unroll
    for (int i = 0; i < 4; i++)
        tile[rl + 8 * i][cl] = ldmix(src, off + (u64)(tr * 32 + rl + 8 * i) * C + tc * 32 + cl, isbf);
    __syncthreads();
#pragma unroll
    for (int i = 0; i < 4; i++)
        dst[(u64)(tc * 32 + rl + 8 * i) * R + tr * 32 + cl] = f2bf(tile[cl][rl + 8 * i]);
}

// ---------------------------------------------------------------------------
// bf16 MFMA GEMM (m97 structure):  C[M,N] = A[M,K] @ Bt[N,K]^T + bias
// Staging via global_load_lds width-16 into linear [128][32] LDS (no VALU
// staging, no ds_writes). 2 barriers per K-step; loads for tile k+1 fly
// under tile k's MFMAs.
// MODE 1: outF = acc+bias+resid (fp32, may alias resid)
// MODE 2: outB = gelu(acc+bias) (bf16)
// MODE 3: fused QKV - bias selected from {bA,bB,bC} by N-tile (bf16 out)
// ---------------------------------------------------------------------------
template <int MODE>
__global__ __launch_bounds__(256, 2) void gemm_bt(
    const u16* __restrict__ A, const u16* __restrict__ Bt,
    const void* __restrict__ bA, const void* __restrict__ bB,
    const void* __restrict__ bC, u64 oB, const float* __restrict__ resid,
    float* __restrict__ outF, u16* __restrict__ outB,
    const int* __restrict__ flagp, int N, int K)
{
    __shared__ __align__(16) u16 sA[128 * 32];
    __shared__ __align__(16) u16 sB[128 * 32];
    int tid = threadIdx.x;
    int lane = tid & 63, wave = tid >> 6;
    int wr = wave >> 1, wc = wave & 1;
    int bn = blockIdx.x, bm = blockIdx.y;
    const u16* Ab = A + (u64)bm * 128 * K;
    const u16* Bb = Bt + (u64)bn * 128 * K;
    int srow = tid >> 2;           // 0..63: row within half-tile
    int scol = (tid & 3) * 8;      // 8-elem (16B) column chunk
    // wave-uniform LDS bases; HW scatters lane*16B after each
    u16* sAw0 = sA + wave * 512;
    u16* sAw1 = sA + 2048 + wave * 512;
    u16* sBw0 = sB + wave * 512;
    u16* sBw1 = sB + 2048 + wave * 512;
    const u16* Ar0 = Ab + (u64)srow * K + scol;
    const u16* Ar1 = Ab + (u64)(srow + 64) * K + scol;
    const u16* Br0 = Bb + (u64)srow * K + scol;
    const u16* Br1 = Bb + (u64)(srow + 64) * K + scol;
    int cl = lane & 15, quad = lane >> 4;

    f32x4 acc[4][4];
    const f32x4 vz = {0.f, 0.f, 0.f, 0.f};
#pragma unroll
    for (int mi = 0; mi < 4; mi++)
#pragma unroll
        for (int ni = 0; ni < 4; ni++) acc[mi][ni] = vz;

    // prologue: stage tile 0
    gll16(Ar0, sAw0); gll16(Ar1, sAw1);
    gll16(Br0, sBw0); gll16(Br1, sBw1);

    for (int k0 = 0; k0 < K; k0 += 32) {
        __syncthreads();   // drains vmcnt(0): tile k resident in LDS
        bf16x8 af[4], bfr[4];
#pragma unroll
        for (int mi = 0; mi < 4; mi++)
            af[mi] = *(const bf16x8*)(sA + (wr * 64 + mi * 16 + cl) * 32 + quad * 8);
#pragma unroll
        for (int ni = 0; ni < 4; ni++)
            bfr[ni] = *(const bf16x8*)(sB + (wc * 64 + ni * 16 + cl) * 32 + quad * 8);
        __syncthreads();   // all waves done reading LDS (lgkm drained)
        int kn = k0 + 32;
        if (kn < K) {      // stage tile k+1; flies under the MFMAs below
            gll16(Ar0 + kn, sAw0); gll16(Ar1 + kn, sAw1);
            gll16(Br0 + kn, sBw0); gll16(Br1 + kn, sBw1);
        }
#pragma unroll
        for (int mi = 0; mi < 4; mi++)
#pragma unroll
            for (int ni = 0; ni < 4; ni++)
                acc[mi][ni] = __builtin_amdgcn_mfma_f32_16x16x32_bf16(
                    af[mi], bfr[ni], acc[mi][ni], 0, 0, 0);
    }

    int isbf = *flagp;
    int rowb = bm * 128 + wr * 64 + quad * 4;   // C/D: col=lane&15, row=quad*4+reg
    int colb = bn * 128 + wc * 64 + cl;
    const void* bp = bA;
    int csub = 0;
    if (MODE == 3) {       // 18 N-tiles: 0-5 Q, 6-11 K, 12-17 V
        int ms = bn / 6;
        bp = (ms == 0) ? bA : (ms == 1) ? bB : bC;
        csub = ms * 768;
    }
#pragma unroll
    for (int ni = 0; ni < 4; ni++) {
        int col = colb + ni * 16;
        float bv = ldmix(bp, oB + (u64)(col - csub), isbf);
#pragma unroll
        for (int mi = 0; mi < 4; mi++) {
#pragma unroll
            for (int r = 0; r < 4; r++) {
                int row = rowb + mi * 16 + r;
                float v = acc[mi][ni][r] + bv;
                if (MODE == 1) {
                    v += resid[(u64)row * N + col];
                    outF[(u64)row * N + col] = v;
                } else {
                    if (MODE == 2) v = 0.5f * v * (1.0f + erff(v * 0.70710678118654752f));
                    outB[(u64)row * N + col] = f2bf(v);
                }
            }
        }
    }
}

// ---------------------------------------------------------------------------
// Attention: one block per (b,h). S=64, DK=64. Q/K/V packed [8192][2304].
// ---------------------------------------------------------------------------
__global__ __launch_bounds__(256) void attn_kernel(
    const u16* __restrict__ QKV, const int* __restrict__ xids, u16* __restrict__ ctx)
{
    constexpr int LDA = 72;
    __shared__ __align__(16) u16 sQ[64 * LDA];
    __shared__ __align__(16) u16 sK[64 * LDA];
    __shared__ __align__(16) u16 sVt[64 * LDA];
    int tid = threadIdx.x;
    int lane = tid & 63, wave = tid >> 6;
    int b = blockIdx.x / 12, h = blockIdx.x % 12;
    {
        int r = tid >> 2, cb = (tid & 3) * 16;
        u64 gbase = ((u64)(b * 64 + r)) * 2304 + h * 64 + cb;
        uint4 q0 = *(const uint4*)(QKV + gbase);
        uint4 q1 = *(const uint4*)(QKV + gbase + 8);
        uint4 k0 = *(const uint4*)(QKV + gbase + 768);
        uint4 k1 = *(const uint4*)(QKV + gbase + 776);
        uint4 v0 = *(const uint4*)(QKV + gbase + 1536);
        uint4 v1 = *(const uint4*)(QKV + gbase + 1544);
        *(uint4*)(sQ + r * LDA + cb) = q0;
        *(uint4*)(sQ + r * LDA + cb + 8) = q1;
        *(uint4*)(sK + r * LDA + cb) = k0;
        *(uint4*)(sK + r * LDA + cb + 8) = k1;
        u16 vt[16];
        *(uint4*)(vt) = v0; *(uint4*)(vt + 8) = v1;
#pragma unroll
        for (int j = 0; j < 16; j++) sVt[(cb + j) * LDA + r] = vt[j];
    }
    __syncthreads();
    int cl = lane & 15, quad = lane >> 4;

    f32x4 sc[4];
    const f32x4 vz = {0.f, 0.f, 0.f, 0.f};
#pragma unroll
    for (int ni = 0; ni < 4; ni++) sc[ni] = vz;
#pragma unroll
    for (int kt = 0; kt < 2; kt++) {
        bf16x8 a = *(const bf16x8*)(sQ + (wave * 16 + cl) * LDA + kt * 32 + quad * 8);
#pragma unroll
        for (int ni = 0; ni < 4; ni++) {
            bf16x8 bb = *(const bf16x8*)(sK + (ni * 16 + cl) * LDA + kt * 32 + quad * 8);
            sc[ni] = __builtin_amdgcn_mfma_f32_16x16x32_bf16(a, bb, sc[ni], 0, 0, 0);
        }
    }
    bool ok[4];
#pragma unroll
    for (int ni = 0; ni < 4; ni++) ok[ni] = xids[b * 64 + ni * 16 + cl] > 0;
    float p[4][4];
#pragma unroll
    for (int r = 0; r < 4; r++) {
        float m = -3.0e38f;
#pragma unroll
        for (int ni = 0; ni < 4; ni++) {
            float s = ok[ni] ? sc[ni][r] * 0.125f : -1e9f;
            p[ni][r] = s;
            m = fmaxf(m, s);
        }
#pragma unroll
        for (int off = 1; off < 16; off <<= 1) m = fmaxf(m, __shfl_xor(m, off));
        float sum = 0.f;
#pragma unroll
        for (int ni = 0; ni < 4; ni++) { float e = __expf(p[ni][r] - m); p[ni][r] = e; sum += e; }
#pragma unroll
        for (int off = 1; off < 16; off <<= 1) sum += __shfl_xor(sum, off);
        float inv = 1.0f / sum;
#pragma unroll
        for (int ni = 0; ni < 4; ni++) p[ni][r] *= inv;
    }
    __syncthreads();
#pragma unroll
    for (int ni = 0; ni < 4; ni++)
#pragma unroll
        for (int r = 0; r < 4; r++)
            sQ[(wave * 16 + quad * 4 + r) * LDA + ni * 16 + cl] = f2bf(p[ni][r]);
    __syncthreads();
    f32x4 o[4];
#pragma unroll
    for (int ni = 0; ni < 4; ni++) o[ni] = vz;
#pragma unroll
    for (int kt = 0; kt < 2; kt++) {
        bf16x8 a = *(const bf16x8*)(sQ + (wave * 16 + cl) * LDA + kt * 32 + quad * 8);
#pragma unroll
        for (int ni = 0; ni < 4; ni++) {
            bf16x8 bb = *(const bf16x8*)(sVt + (ni * 16 + cl) * LDA + kt * 32 + quad * 8);
            o[ni] = __builtin_amdgcn_mfma_f32_16x16x32_bf16(a, bb, o[ni], 0, 0, 0);
        }
    }
#pragma unroll
    for (int ni = 0; ni < 4; ni++)
#pragma unroll
        for (int r = 0; r < 4; r++)
            ctx[((u64)(b * 64 + wave * 16 + quad * 4 + r)) * 768 + h * 64 + ni * 16 + cl] =
                f2bf(o[ni][r]);
}

// ---------------------------------------------------------------------------
// LayerNorm; outF may alias X (row read into regs first). Writes fp32
// (residual path) + bf16 (GEMM-A path). If isfinal, also writes d_out in
// the detected dtype. g/b indexed at oB+c.
// ---------------------------------------------------------------------------
__global__ __launch_bounds__(256) void ln_kernel(
    const float* __restrict__ X, const void* __restrict__ g, const void* __restrict__ bta,
    const int* __restrict__ flagp, float* __restrict__ outF, u16* __restrict__ outH,
    void* __restrict__ outD, int isfinal, u64 oB)
{
    int isbf = *flagp;
    int t = blockIdx.x;
    const float* xr = X + (u64)t * 768;
    int tid = threadIdx.x;
    float v0 = xr[tid], v1 = xr[tid + 256], v2 = xr[tid + 512];
    float s = v0 + v1 + v2;
    float sq = v0 * v0 + v1 * v1 + v2 * v2;
#pragma unroll
    for (int off = 1; off < 64; off <<= 1) { s += __shfl_xor(s, off); sq += __shfl_xor(sq, off); }
    __shared__ float red[8];
    int lane = tid & 63, wave = tid >> 6;
    if (lane == 0) { red[wave] = s; red[4 + wave] = sq; }
    __syncthreads();
    s = red[0] + red[1] + red[2] + red[3];
    sq = red[4] + red[5] + red[6] + red[7];
    float mu = s * (1.0f / 768.0f);
    float var = sq * (1.0f / 768.0f) - mu * mu;
    float rs = rsqrtf(var + 1e-5f);
    float* of = outF + (u64)t * 768;
#pragma unroll
    for (int i = 0; i < 3; i++) {
        int c = tid + i * 256;
        float v = (i == 0) ? v0 : (i == 1) ? v1 : v2;
        float y = (v - mu) * rs * ldmix(g, oB + c, isbf) + ldmix(bta, oB + c, isbf);
        of[c] = y;
        outH[(u64)t * 768 + c] = f2bf(y);
        if (isfinal) {
            if (isbf) ((u16*)outD)[(u64)t * 768 + c] = f2bf(y);
            else      ((float*)outD)[(u64)t * 768 + c] = y;
        }
    }
}

// ---------------------------------------------------------------------------
extern "C" void kernel_launch(void* const* d_in, const int* in_sizes, int n_in,
                              void* d_out, int out_size, void* d_ws, size_t ws_size,
                              hipStream_t stream)
{
    const int* x    = (const int*)d_in[0];
    const int* seg  = (const int*)d_in[1];
    const void* tok = d_in[2];
    const void* sege= d_in[3];
    const void* Wq  = d_in[4];
    const void* bq  = d_in[5];
    const void* Wk  = d_in[6];
    const void* bk  = d_in[7];
    const void* Wv  = d_in[8];
    const void* bv  = d_in[9];
    const void* Wo  = d_in[10];
    const void* bo  = d_in[11];
    const void* lng = d_in[12];
    const void* lnb = d_in[13];
    const void* W1  = d_in[14];
    const void* b1  = d_in[15];
    const void* W2  = d_in[16];
    const void* b2  = d_in[17];

    const u64 ND = 8192ull * 768ull;
    char* p = (char*)d_ws;
    auto alloc = [&](size_t bytes) { char* q = p; p += (bytes + 255) & ~(size_t)255; return q; };
    int*   flag = (int*)alloc(256);
    float* hF   = (float*)alloc(ND * 4);
    float* xF   = (float*)alloc(ND * 4);
    u16*   hB   = (u16*)alloc(ND * 2);
    u16*   xB   = (u16*)alloc(ND * 2);
    u16*   qkvB = (u16*)alloc(ND * 3 * 2);   // [8192][2304]; ffB aliases qkv+ctx
    u16*   ctxB = (u16*)alloc(ND * 2);
    u16*   ffB  = qkvB;                       // 8192*3072*2 = qkv(3*ND*2)+ctx(ND*2)
    u16*   Wt   = (u16*)alloc(7077888ull * 2);

    detect_kernel<<<1, 64, 0, stream>>>((const unsigned*)tok, flag);
    embed_kernel<<<8192, 256, 0, stream>>>(x, seg, tok, sege, flag, hF, hB);

    dim3 g768(6, 64), g2304(18, 64), g3072(24, 64);
    for (int l = 0; l < 12; l++) {
        const u64 oS = (u64)l * 589824ull, oF = (u64)l * 2359296ull;
        const u64 oB = (u64)l * 768ull, oB1 = (u64)l * 3072ull;
        transpose6<<<6912, 256, 0, stream>>>(Wq, Wk, Wv, Wo, W1, W2, Wt, flag, oS, oF);
        // fused QKV: [8192,768] @ [2304,768]^T -> [8192,2304]
        gemm_bt<3><<<g2304, 256, 0, stream>>>(hB, Wt, bq, bk, bv, oB,
                                              nullptr, nullptr, qkvB, flag, 2304, 768);
        attn_kernel<<<1536, 256, 0, stream>>>(qkvB, x, ctxB);
        gemm_bt<1><<<g768, 256, 0, stream>>>(ctxB, Wt + 1769472, bo, nullptr, nullptr, oB,
                                             hF, xF, nullptr, flag, 768, 768);
        ln_kernel<<<8192, 256, 0, stream>>>(xF, lng, lnb, flag, xF, xB, nullptr, 0, oB);
        gemm_bt<2><<<g3072, 256, 0, stream>>>(xB, Wt + 2359296, b1, nullptr, nullptr, oB1,
                                              nullptr, nullptr, ffB, flag, 3072, 768);
        gemm_bt<1><<<g768, 256, 0, stream>>>(ffB, Wt + 4718592, b2, nullptr, nullptr, oB,
                                             xF, xF, nullptr, flag, 768, 3072);
        ln_kernel<<<8192, 256, 0, stream>>>(xF, lng, lnb, flag, hF, hB,
                                            (l == 11) ? d_out : nullptr,
                                            (l == 11) ? 1 : 0, oB);
    }
}